// Round 5
// baseline (1299.823 us; speedup 1.0000x reference)
//
#include <hip/hip_runtime.h>
#include <cstdint>
#include <cstddef>

typedef unsigned short u16;
typedef __attribute__((ext_vector_type(8))) short short8;
typedef __attribute__((ext_vector_type(4))) float f32x4;

#define B_DIM 16
#define C_DIM 64
#define T_DIM 64
#define N_DIM 1024
#define KS_DIM 3
#define KSTEPS 16              // K=1024 / BK=64

// Dynamic LDS layout (u16 units):
//   A dbuf p @ p*16384        : [ksub][256 rows][32 m] (16KB each sub) -> 64KB
//   B dbuf p @ 32768+p*12288  : [ksub][192 rows][32 m] (12KB each sub) -> 48KB
//   Z (epilogue) @ 0          : [256][200] bf16 (100KB)
// total 114688 bytes

__device__ __forceinline__ u16 f2bf(float f) {
  union { float f; uint32_t u; } v; v.f = f;
  uint32_t r = (v.u + 0x7FFFu + ((v.u >> 16) & 1u)) >> 16;  // RNE
  return (u16)r;
}
__device__ __forceinline__ uint32_t pk2(float a, float b) {
  return (uint32_t)f2bf(a) | ((uint32_t)f2bf(b) << 16);
}
__device__ __forceinline__ void gload_lds16(const void* g, void* l) {
  __builtin_amdgcn_global_load_lds(
      (const __attribute__((address_space(1))) void*)g,
      (__attribute__((address_space(3))) void*)l, 16, 0, 0);
}

__global__ void k_convert_lk(const float* __restrict__ Lk, u16* __restrict__ Lkb) {
  size_t idx = (size_t)blockIdx.x * blockDim.x + threadIdx.x;
  const float4* s = (const float4*)(Lk + idx * 8);
  float4 f0 = s[0], f1 = s[1];
  short8 h;
  h[0] = (short)f2bf(f0.x); h[1] = (short)f2bf(f0.y);
  h[2] = (short)f2bf(f0.z); h[3] = (short)f2bf(f0.w);
  h[4] = (short)f2bf(f1.x); h[5] = (short)f2bf(f1.y);
  h[6] = (short)f2bf(f1.z); h[7] = (short)f2bf(f1.w);
  *(short8*)(Lkb + idx * 8) = h;
}

__global__ void k_convert_theta(const float* __restrict__ th, u16* __restrict__ thT) {
  int f = blockIdx.x * blockDim.x + threadIdx.x;
  if (f < C_DIM * C_DIM * KS_DIM) {
    int o = f / 192, ik = f % 192, k = ik >> 6, i = ik & 63;
    thT[f] = f2bf(th[(i * 64 + o) * 3 + k]);
  }
}

// v4: 256x192 tile (4 t-slices), BK=64, 8 waves (4M x 2N, wave=64x96),
// counted-vmcnt pipeline, v1-proven [row][32]+XOR swizzle per K-subtile.
__global__ __launch_bounds__(512, 2)
void k_main(const float* __restrict__ x, const u16* __restrict__ Lkb,
            const u16* __restrict__ thT, const float* __restrict__ bias,
            float* __restrict__ out) {
  extern __shared__ __align__(16) u16 smem[];

  const int tid = threadIdx.x;
  const int wv = tid >> 6, ln = tid & 63, lg = ln >> 4, l16 = ln & 15;
  const int wr = wv >> 1, wc = wv & 1;     // 4M x 2N wave grid

  // T1 bijective XCD swizzle (4096 % 8 == 0): 16 n-groups of one slice-group
  // land on one XCD -> x slice read from HBM once, 15x from L2.
  const int bid = blockIdx.x;
  const int work = ((bid & 7) << 9) + (bid >> 3);
  const int sg = work >> 4, ng = work & 15;   // slice-group, n-group
  const int bb = sg >> 4, t0 = (sg & 15) << 2;

  const f32x4 vzero = {0.f, 0.f, 0.f, 0.f};
  f32x4 acc[4][6];
#pragma unroll
  for (int a = 0; a < 4; ++a)
#pragma unroll
    for (int c = 0; c < 6; ++c) acc[a][c] = vzero;

  // ---- A staging geometry: 64KB fp32/step = 4096 float4; 8 per thread ----
  // chunk c2 = u*512 + tid: row = c2>>4 = u*32 + (tid>>4), fchunk = tid&15
  const int tr = tid >> 4;          // 0..31
  const int fch = tid & 15;
  const int ksb_a = fch >> 3;       // m-half (ksub)
  const int g2 = (fch & 7) >> 1;    // 16B group within 64B row
  const int hf = fch & 1;           // 8B half within group
  const int swa = (tr >> 1) & 3;    // row swizzle (u-independent: u*32 ≡ 0 mod 4)
  const float* a_base = x + (((size_t)bb * C_DIM + tr) * T_DIM + t0) * N_DIM + (fch << 2);
#define AOFF(u) ((((u) & 1) * 32 * T_DIM + (((u) >> 1))) * N_DIM)
  const int a_dst_c = ksb_a * 8192 + tr * 32 + ((g2 ^ swa) << 3) + (hf << 2);

  // ---- B staging: 1536 16B-chunks/step, 3 per thread (DMA) ----
  const u16* b_src[3];
  int b_dst_c[3];  // u16 offset of wave-uniform dest base within B buffer
#pragma unroll
  for (int it = 0; it < 3; ++it) {
    int c = (it << 9) + tid;                 // 0..1535
    int ksb = (c >= 768) ? 1 : 0;            // wave-uniform (boundary at wave edge)
    int rem = c - ksb * 768;
    int brow = rem >> 2, g = rem & 3;
    int k = brow >> 6, nl = brow & 63;
    int gs = g ^ ((brow >> 1) & 3);          // pre-swizzled global source group
    b_src[it] = Lkb + ((size_t)(k * N_DIM + ng * 64 + nl)) * N_DIM + (ksb << 5) + (gs << 3);
    b_dst_c[it] = ((it << 9) + (wv << 6)) << 3;   // chunk*16B in u16 (=*8)
  }

  float4 q[8];

  // ---- prologue: B(0)->buf0 DMA, A(0) load+write, A(1) in flight ----
#pragma unroll
  for (int it = 0; it < 3; ++it)
    gload_lds16(b_src[it], (char*)(smem + 32768) + ((size_t)b_dst_c[it] << 1));
#pragma unroll
  for (int u = 0; u < 8; ++u) q[u] = *(const float4*)(a_base + AOFF(u));
  asm volatile("s_waitcnt vmcnt(0)" ::: "memory");
#pragma unroll
  for (int u = 0; u < 8; ++u) {
    uint2 w; w.x = pk2(q[u].x, q[u].y); w.y = pk2(q[u].z, q[u].w);
    *(uint2*)(smem + a_dst_c + u * 1024) = w;
  }
#pragma unroll
  for (int u = 0; u < 8; ++u) q[u] = *(const float4*)(a_base + AOFF(u) + 64);
  asm volatile("s_waitcnt lgkmcnt(0)" ::: "memory");
  __builtin_amdgcn_s_barrier();

  for (int kk = 0; kk < KSTEPS; ++kk) {
    const int p = kk & 1, pn = p ^ 1;
    const int wn = (kk + 1) & (KSTEPS - 1);
    // @a: issue B(kk+1) DMA -> B[pn] (3 loads; stay in flight through compute)
    u16* Bn = smem + 32768 + pn * 12288;
#pragma unroll
    for (int it = 0; it < 3; ++it)
      gload_lds16(b_src[it] + wn * 64, (char*)Bn + ((size_t)b_dst_c[it] << 1));
    // @b: retire B(kk) DMA + A(kk+1) reg-loads; leave the 3 just-issued flying
    asm volatile("s_waitcnt vmcnt(3)" ::: "memory");
    // @c: write A(kk+1) -> A[pn]
    {
      u16* ad = smem + pn * 16384 + a_dst_c;
#pragma unroll
      for (int u = 0; u < 8; ++u) {
        uint2 w; w.x = pk2(q[u].x, q[u].y); w.y = pk2(q[u].z, q[u].w);
        *(uint2*)(ad + u * 1024) = w;
      }
    }
    // @d: issue A(kk+2) reg-loads (wrapped at tail; drained by final sync)
    {
      const int w2 = (kk + 2) & (KSTEPS - 1);
#pragma unroll
      for (int u = 0; u < 8; ++u) q[u] = *(const float4*)(a_base + AOFF(u) + w2 * 64);
    }
    // @e: publish A(kk+1)/B(kk) to all waves
    asm volatile("s_waitcnt lgkmcnt(0)" ::: "memory");
    __builtin_amdgcn_s_barrier();
    // @f: compute step kk: 48 MFMA/wave from A[p],B[p]
    const u16* Ab = smem + p * 16384;
    const u16* Bb = smem + 32768 + p * 12288;
#pragma unroll
    for (int ks = 0; ks < 2; ++ks) {
      short8 af[4];
#pragma unroll
      for (int mi = 0; mi < 4; ++mi) {
        int row = wr * 64 + mi * 16 + l16;
        af[mi] = *(const short8*)(Ab + ks * 8192 + row * 32 + ((lg ^ ((row >> 1) & 3)) << 3));
      }
      __builtin_amdgcn_s_setprio(1);
#pragma unroll
      for (int ci = 0; ci < 6; ++ci) {
        int brow = wc * 96 + ci * 16 + l16;
        short8 bfr = *(const short8*)(Bb + ks * 6144 + brow * 32 + ((lg ^ ((brow >> 1) & 3)) << 3));
#pragma unroll
        for (int mi = 0; mi < 4; ++mi)
          acc[mi][ci] = __builtin_amdgcn_mfma_f32_16x16x32_bf16(af[mi], bfr, acc[mi][ci], 0, 0, 0);
      }
      __builtin_amdgcn_s_setprio(0);
    }
    // @g: all waves done reading [p] buffers
    asm volatile("s_waitcnt lgkmcnt(0)" ::: "memory");
    __builtin_amdgcn_s_barrier();
  }

  __syncthreads();   // full drain (incl. wrapped DMA) before Z overwrites buffers

  // ---- transpose z -> Z[(s*64+nl)][k*64+i], rows padded to 200 u16 ----
#pragma unroll
  for (int mi = 0; mi < 4; ++mi)
#pragma unroll
    for (int ci = 0; ci < 6; ++ci) {
      int c = wc * 96 + ci * 16 + l16;
      int k = c >> 6, nl = c & 63;
      int zrow = wr * 64 + nl;              // s == wr
      int ib = mi * 16 + lg * 4;
      u16* zp = smem + zrow * 200 + k * 64 + ib;
      *(uint32_t*)zp = pk2(acc[mi][ci][0], acc[mi][ci][1]);
      *(uint32_t*)(zp + 2) = pk2(acc[mi][ci][2], acc[mi][ci][3]);
    }
  __syncthreads();

  // ---- mix GEMM: out[o][n] = sum_ik thT[o][ik] * Z[(s,nl)][ik] ----
  f32x4 acc2[4][2];
#pragma unroll
  for (int a = 0; a < 4; ++a)
#pragma unroll
    for (int c = 0; c < 2; ++c) acc2[a][c] = vzero;
  const int s_e = wv >> 1, h_e = wv & 1;    // wave -> (slice, col-half)
#pragma unroll
  for (int ks = 0; ks < 6; ++ks) {
    short8 af2[4];
#pragma unroll
    for (int mo = 0; mo < 4; ++mo)
      af2[mo] = *(const short8*)(thT + (mo * 16 + l16) * 192 + ks * 32 + lg * 8);
#pragma unroll
    for (int cj = 0; cj < 2; ++cj) {
      int nl = h_e * 32 + cj * 16 + l16;
      short8 bfr = *(const short8*)(smem + (s_e * 64 + nl) * 200 + ks * 32 + lg * 8);
#pragma unroll
      for (int mo = 0; mo < 4; ++mo)
        acc2[mo][cj] = __builtin_amdgcn_mfma_f32_16x16x32_bf16(af2[mo], bfr, acc2[mo][cj], 0, 0, 0);
    }
  }

  // ---- epilogue: + bias + fp32 residual, relu, store ----
#pragma unroll
  for (int mo = 0; mo < 4; ++mo)
#pragma unroll
    for (int cj = 0; cj < 2; ++cj) {
      int nl = h_e * 32 + cj * 16 + l16;
      int n = ng * 64 + nl;
#pragma unroll
      for (int r = 0; r < 4; ++r) {
        int o = mo * 16 + lg * 4 + r;
        size_t oi = (((size_t)bb * C_DIM + o) * T_DIM + t0 + s_e) * N_DIM + n;
        float v = acc2[mo][cj][r] + bias[o] + x[oi];
        out[oi] = v > 0.f ? v : 0.f;
      }
    }
}

extern "C" void kernel_launch(void* const* d_in, const int* in_sizes, int n_in,
                              void* d_out, int out_size, void* d_ws, size_t ws_size,
                              hipStream_t stream) {
  (void)in_sizes; (void)n_in; (void)out_size; (void)ws_size;
  const float* x     = (const float*)d_in[0];
  const float* Lk    = (const float*)d_in[1];
  const float* theta = (const float*)d_in[2];
  const float* bias  = (const float*)d_in[3];
  float* out = (float*)d_out;

  u16* Lkb = (u16*)d_ws;                                               // 6 MB
  u16* thT = (u16*)((char*)d_ws + (size_t)KS_DIM * N_DIM * N_DIM * 2); // 24 KB

  k_convert_lk<<<KS_DIM * N_DIM * N_DIM / 8 / 256, 256, 0, stream>>>(Lk, Lkb);
  k_convert_theta<<<(C_DIM * C_DIM * KS_DIM + 255) / 256, 256, 0, stream>>>(theta, thT);

  hipFuncSetAttribute((const void*)k_main, hipFuncAttributeMaxDynamicSharedMemorySize, 114688);
  k_main<<<B_DIM * T_DIM / 4 * 16, 512, 114688, stream>>>(x, Lkb, thT, bias, out);
}